// Round 2
// baseline (236.697 us; speedup 1.0000x reference)
//
#include <hip/hip_runtime.h>
#include <hip/hip_bf16.h>

typedef __bf16 bhalf;
typedef __attribute__((ext_vector_type(8))) __bf16 bhalf8;
typedef __attribute__((ext_vector_type(4))) __bf16 bhalf4;
typedef __attribute__((ext_vector_type(4))) float  f32x4;
typedef __attribute__((ext_vector_type(4))) short  s16x4;

#define NB   16
#define SEQ  2048
#define DIN  512
#define DOUT 64
#define NTOK (NB*SEQ)
#define NSPLIT 4
#define KVPER (SEQ/NSPLIT)     // 512 kv per wave

// ws layout
#define WT_BYTES (192*512*2)              // 196608 B, 16B-aligned
#define Q_OFF    ((size_t)WT_BYTES)
#define QKV_BYTES ((size_t)NTOK*DOUT*2)   // 4 MiB each
#define K_OFF    (Q_OFF + QKV_BYTES)
#define VT_OFF   (K_OFF + QKV_BYTES)

// ---------------------------------------------------------------------------
// Kernel 0: W[0..2] fp32 [slot][k][col] -> Wt bf16 [n=slot*64+col][k]
// Fold (1/8)*log2(e) into slot 0 (Q) so attention scores are in exp2 units.
__global__ __launch_bounds__(256) void prep_w(const float* __restrict__ wk,
                                              bhalf* __restrict__ wt) {
  int tid  = blockIdx.x*256 + threadIdx.x;     // 0..98303
  int slot = tid >> 15;                        // /(512*64)
  int rem  = tid & 32767;
  int k    = rem >> 6;
  int col  = rem & 63;
  float v  = wk[tid];                          // coalesced read
  if (slot == 0) v *= 0.18033688011112042f;    // (1/8)*log2(e), folded scale
  wt[(size_t)(slot*64 + col)*DIN + k] = (bhalf)v;
}

// ---------------------------------------------------------------------------
// Kernel 1: QKV projection. 4 waves/block, wave = 16 token rows, N=192, K=512.
__global__ __launch_bounds__(256) void proj_qkv(const float* __restrict__ x,
    const bhalf* __restrict__ wt, bhalf* __restrict__ qb,
    bhalf* __restrict__ kb, bhalf* __restrict__ vtb) {
  __shared__ bhalf vlds[4][64][24];
  const int lane = threadIdx.x & 63;
  const int wv   = threadIdx.x >> 6;
  const int r16  = lane & 15;
  const int g    = lane >> 4;
  const int tokbase = blockIdx.x*64 + wv*16;

  f32x4 acc[12];
#pragma unroll
  for (int i = 0; i < 12; ++i) acc[i] = (f32x4){0.f, 0.f, 0.f, 0.f};

  const float* xrow = x  + (size_t)(tokbase + r16)*DIN + g*8;
  const bhalf* wrow = wt + (size_t)r16*DIN + g*8;

  for (int kk = 0; kk < 16; ++kk) {
    f32x4 xa = *(const f32x4*)(xrow + kk*32);
    f32x4 xc = *(const f32x4*)(xrow + kk*32 + 4);
    bhalf8 a;
    a[0]=(bhalf)xa[0]; a[1]=(bhalf)xa[1]; a[2]=(bhalf)xa[2]; a[3]=(bhalf)xa[3];
    a[4]=(bhalf)xc[0]; a[5]=(bhalf)xc[1]; a[6]=(bhalf)xc[2]; a[7]=(bhalf)xc[3];
#pragma unroll
    for (int nt = 0; nt < 12; ++nt) {
      bhalf8 bfrag = *(const bhalf8*)(wrow + (size_t)nt*16*DIN + kk*32);
      acc[nt] = __builtin_amdgcn_mfma_f32_16x16x32_bf16(a, bfrag, acc[nt], 0, 0, 0);
    }
  }

#pragma unroll
  for (int nt = 0; nt < 8; ++nt) {
    bhalf* dst = (nt < 4) ? qb : kb;
    int col = (nt & 3)*16 + r16;
#pragma unroll
    for (int rr = 0; rr < 4; ++rr) {
      int tok = tokbase + g*4 + rr;
      dst[(size_t)tok*DOUT + col] = (bhalf)acc[nt][rr];
    }
  }
#pragma unroll
  for (int nt = 8; nt < 12; ++nt) {
#pragma unroll
    for (int rr = 0; rr < 4; ++rr) {
      vlds[wv][(nt-8)*16 + r16][g*4 + rr] = (bhalf)acc[nt][rr];
    }
  }
  __syncthreads();
  {
    int f      = threadIdx.x & 63;
    int tb     = blockIdx.x*64 + wv*16;
    int b      = (blockIdx.x*64) >> 11;
    int tokloc = tb & 2047;
    bhalf8 v0 = *(const bhalf8*)&vlds[wv][f][0];
    bhalf8 v1 = *(const bhalf8*)&vlds[wv][f][8];
    bhalf* dst = vtb + (size_t)b*(DOUT*SEQ) + (size_t)f*SEQ + tokloc;
    *(bhalf8*)dst       = v0;
    *(bhalf8*)(dst + 8) = v1;
  }
}

// ---------------------------------------------------------------------------
// Kernel 2: flash attention, KV-split x4 within a block.
// Block = one 16-row q-tile; wave wv handles kv in [wv*512, wv*512+512),
// KVBLK=32 per iteration, double-buffered register prefetch of K/V frags.
// Partials (O, m, l) combined in LDS at the end.
__global__ __launch_bounds__(256) void attn(const bhalf* __restrict__ qb,
    const bhalf* __restrict__ kb, const bhalf* __restrict__ vtb,
    float* __restrict__ out) {
  __shared__ float po[NSPLIT][16][65];   // [split][q][d], pad 65 vs bank conflicts
  __shared__ float pm[NSPLIT][16];
  __shared__ float pl[NSPLIT][16];

  const int lane = threadIdx.x & 63;
  const int wv   = threadIdx.x >> 6;     // split index 0..3
  const int r16  = lane & 15;
  const int g    = lane >> 4;

  // XCD-bijective swizzle: XCD x owns q-tiles [x*256, x*256+256) = 2 batches.
  const int qtile = (blockIdx.x & 7)*256 + (blockIdx.x >> 3);   // 0..2047
  const int qbase = qtile*16;
  const int b     = qbase >> 11;

  const bhalf* qrow = qb + (size_t)(qbase + r16)*DOUT + g*8;
  const bhalf8 qf0 = *(const bhalf8*)(qrow);
  const bhalf8 qf1 = *(const bhalf8*)(qrow + 32);

  const bhalf* kbat = kb  + (size_t)b*SEQ*DOUT;
  const bhalf* vbat = vtb + (size_t)b*DOUT*SEQ;
  const int kv0 = wv * KVPER;

  f32x4 o0 = {0.f,0.f,0.f,0.f}, o1 = o0, o2 = o0, o3 = o0;
  float m = -INFINITY, lsum = 0.f;

  bhalf8 kf[2][4];
  s16x4  vf[2][8];

  auto loadK = [&](int kv, int bi) {
    const bhalf* kr = kbat + (size_t)(kv + r16)*DOUT + g*8;
    kf[bi][0] = *(const bhalf8*)(kr);
    kf[bi][1] = *(const bhalf8*)(kr + 32);
    kf[bi][2] = *(const bhalf8*)(kr + 16*DOUT);
    kf[bi][3] = *(const bhalf8*)(kr + 16*DOUT + 32);
  };
  auto loadV = [&](int kv, int bi) {
    const bhalf* vr = vbat + (size_t)r16*SEQ + kv + g*4;
#pragma unroll
    for (int dt = 0; dt < 4; ++dt) {
      vf[bi][dt]   = __builtin_bit_cast(s16x4, *(const bhalf4*)(vr + dt*16*SEQ));
      vf[bi][4+dt] = __builtin_bit_cast(s16x4, *(const bhalf4*)(vr + dt*16*SEQ + 16));
    }
  };

  loadK(kv0, 0);
  loadV(kv0, 0);

#pragma unroll
  for (int it = 0; it < KVPER/32; ++it) {          // 16 iterations of 32 kv
    const int cur = it & 1;
    const int nxt = cur ^ 1;
    if (it < KVPER/32 - 1) {                        // prefetch next 32-kv chunk
      loadK(kv0 + (it+1)*32, nxt);
      loadV(kv0 + (it+1)*32, nxt);
    }

    f32x4 sa = {0.f,0.f,0.f,0.f}, sb = sa;
    sa = __builtin_amdgcn_mfma_f32_16x16x32_bf16(kf[cur][0], qf0, sa, 0, 0, 0);
    sa = __builtin_amdgcn_mfma_f32_16x16x32_bf16(kf[cur][1], qf1, sa, 0, 0, 0);
    sb = __builtin_amdgcn_mfma_f32_16x16x32_bf16(kf[cur][2], qf0, sb, 0, 0, 0);
    sb = __builtin_amdgcn_mfma_f32_16x16x32_bf16(kf[cur][3], qf1, sb, 0, 0, 0);
    // sa[r] = S^T[kv + g*4 + r][q=r16], sb[r] = S^T[kv+16+g*4+r][q=r16]

    float bm = fmaxf(fmaxf(fmaxf(sa[0], sa[1]), fmaxf(sa[2], sa[3])),
                     fmaxf(fmaxf(sb[0], sb[1]), fmaxf(sb[2], sb[3])));
    bm = fmaxf(bm, __shfl_xor(bm, 16));
    bm = fmaxf(bm, __shfl_xor(bm, 32));

    if (__any(bm > m)) {
      float mnew  = fmaxf(m, bm);
      float alpha = exp2f(m - mnew);
      m = mnew;
      lsum *= alpha;
      float a0 = __shfl(alpha, g*4 + 0, 16);
      float a1 = __shfl(alpha, g*4 + 1, 16);
      float a2 = __shfl(alpha, g*4 + 2, 16);
      float a3 = __shfl(alpha, g*4 + 3, 16);
      f32x4 av = {a0, a1, a2, a3};
      o0 *= av; o1 *= av; o2 *= av; o3 *= av;
    }

    f32x4 pa_f, pb_f;
#pragma unroll
    for (int r = 0; r < 4; ++r) { pa_f[r] = exp2f(sa[r] - m); pb_f[r] = exp2f(sb[r] - m); }
    float ps = (pa_f[0]+pa_f[1]) + (pa_f[2]+pa_f[3])
             + (pb_f[0]+pb_f[1]) + (pb_f[2]+pb_f[3]);
    ps += __shfl_xor(ps, 16);
    ps += __shfl_xor(ps, 32);
    lsum += ps;

    bhalf4 pva, pvb;
#pragma unroll
    for (int r = 0; r < 4; ++r) { pva[r] = (bhalf)pa_f[r]; pvb[r] = (bhalf)pb_f[r]; }
    s16x4 paa = __builtin_bit_cast(s16x4, pva);
    s16x4 pab = __builtin_bit_cast(s16x4, pvb);

    o0 = __builtin_amdgcn_mfma_f32_16x16x16bf16_1k(paa, vf[cur][0], o0, 0, 0, 0);
    o1 = __builtin_amdgcn_mfma_f32_16x16x16bf16_1k(paa, vf[cur][1], o1, 0, 0, 0);
    o2 = __builtin_amdgcn_mfma_f32_16x16x16bf16_1k(paa, vf[cur][2], o2, 0, 0, 0);
    o3 = __builtin_amdgcn_mfma_f32_16x16x16bf16_1k(paa, vf[cur][3], o3, 0, 0, 0);
    o0 = __builtin_amdgcn_mfma_f32_16x16x16bf16_1k(pab, vf[cur][4], o0, 0, 0, 0);
    o1 = __builtin_amdgcn_mfma_f32_16x16x16bf16_1k(pab, vf[cur][5], o1, 0, 0, 0);
    o2 = __builtin_amdgcn_mfma_f32_16x16x16bf16_1k(pab, vf[cur][6], o2, 0, 0, 0);
    o3 = __builtin_amdgcn_mfma_f32_16x16x16bf16_1k(pab, vf[cur][7], o3, 0, 0, 0);
  }

  // ---- write per-split partials (unnormalized O, m, l) to LDS ----
  {
    f32x4 od[4] = {o0, o1, o2, o3};
#pragma unroll
    for (int dt = 0; dt < 4; ++dt)
#pragma unroll
      for (int rr = 0; rr < 4; ++rr)
        po[wv][g*4 + rr][dt*16 + r16] = od[dt][rr];
    if (g == 0) { pm[wv][r16] = m; pl[wv][r16] = lsum; }
  }
  __syncthreads();

  // ---- combine 4 splits: 256 threads, each owns (q = tid>>4, 4 d's) ----
  {
    int q  = threadIdx.x >> 4;
    int db = (threadIdx.x & 15) * 4;
    float m0 = pm[0][q], m1 = pm[1][q], m2 = pm[2][q], m3 = pm[3][q];
    float M  = fmaxf(fmaxf(m0, m1), fmaxf(m2, m3));
    float w0 = exp2f(m0 - M), w1 = exp2f(m1 - M),
          w2 = exp2f(m2 - M), w3 = exp2f(m3 - M);
    float L  = pl[0][q]*w0 + pl[1][q]*w1 + pl[2][q]*w2 + pl[3][q]*w3;
    float inv = 1.0f / L;
    float* obase = out + (size_t)(qbase + q)*DOUT + db;
#pragma unroll
    for (int j = 0; j < 4; ++j) {
      obase[j] = (po[0][q][db+j]*w0 + po[1][q][db+j]*w1 +
                  po[2][q][db+j]*w2 + po[3][q][db+j]*w3) * inv;
    }
  }
}

// ---------------------------------------------------------------------------
extern "C" void kernel_launch(void* const* d_in, const int* in_sizes, int n_in,
                              void* d_out, int out_size, void* d_ws, size_t ws_size,
                              hipStream_t stream) {
  const float* x  = (const float*)d_in[0];   // [16,2048,512] fp32
  const float* wk = (const float*)d_in[1];   // [1000,512,64] fp32 (slots 0..2 used)
  float* out = (float*)d_out;                // [16,2048,64] fp32

  char* ws = (char*)d_ws;
  bhalf* wt = (bhalf*)(ws);
  bhalf* qq = (bhalf*)(ws + Q_OFF);
  bhalf* kk = (bhalf*)(ws + K_OFF);
  bhalf* vt = (bhalf*)(ws + VT_OFF);

  prep_w  <<<dim3(384), dim3(256), 0, stream>>>(wk, wt);
  proj_qkv<<<dim3(512), dim3(256), 0, stream>>>(x, wt, qq, kk, vt);
  attn    <<<dim3(2048), dim3(256), 0, stream>>>(qq, kk, vt, out);
}

// Round 3
// 128.687 us; speedup vs baseline: 1.8393x; 1.8393x over previous
//
#include <hip/hip_runtime.h>
#include <hip/hip_bf16.h>

typedef __bf16 bhalf;
typedef __attribute__((ext_vector_type(8)))  __bf16 bhalf8;
typedef __attribute__((ext_vector_type(4)))  float  f32x4;
typedef __attribute__((ext_vector_type(16))) float  f32x16;
typedef __attribute__((ext_vector_type(4)))  unsigned int u32x4;

#define NB   16
#define SEQ  2048
#define DIN  512
#define DOUT 64
#define NTOK (NB*SEQ)
#define NSPLIT 4
#define KVPER (SEQ/NSPLIT)     // 512 kv per wave

// ws layout
#define WT_BYTES (192*512*2)
#define Q_OFF    ((size_t)WT_BYTES)
#define QKV_BYTES ((size_t)NTOK*DOUT*2)
#define K_OFF    (Q_OFF + QKV_BYTES)
#define VT_OFF   (K_OFF + QKV_BYTES)

// ---------------------------------------------------------------------------
__global__ __launch_bounds__(256) void prep_w(const float* __restrict__ wk,
                                              bhalf* __restrict__ wt) {
  int tid  = blockIdx.x*256 + threadIdx.x;
  int slot = tid >> 15;
  int rem  = tid & 32767;
  int k    = rem >> 6;
  int col  = rem & 63;
  float v  = wk[tid];
  if (slot == 0) v *= 0.18033688011112042f;    // (1/8)*log2(e)
  wt[(size_t)(slot*64 + col)*DIN + k] = (bhalf)v;
}

// ---------------------------------------------------------------------------
__global__ __launch_bounds__(256) void proj_qkv(const float* __restrict__ x,
    const bhalf* __restrict__ wt, bhalf* __restrict__ qb,
    bhalf* __restrict__ kb, bhalf* __restrict__ vtb) {
  __shared__ bhalf vlds[4][64][24];
  const int lane = threadIdx.x & 63;
  const int wv   = threadIdx.x >> 6;
  const int r16  = lane & 15;
  const int g    = lane >> 4;
  const int tokbase = blockIdx.x*64 + wv*16;

  f32x4 acc[12];
#pragma unroll
  for (int i = 0; i < 12; ++i) acc[i] = (f32x4){0.f, 0.f, 0.f, 0.f};

  const float* xrow = x  + (size_t)(tokbase + r16)*DIN + g*8;
  const bhalf* wrow = wt + (size_t)r16*DIN + g*8;

  for (int kk = 0; kk < 16; ++kk) {
    f32x4 xa = *(const f32x4*)(xrow + kk*32);
    f32x4 xc = *(const f32x4*)(xrow + kk*32 + 4);
    bhalf8 a;
    a[0]=(bhalf)xa[0]; a[1]=(bhalf)xa[1]; a[2]=(bhalf)xa[2]; a[3]=(bhalf)xa[3];
    a[4]=(bhalf)xc[0]; a[5]=(bhalf)xc[1]; a[6]=(bhalf)xc[2]; a[7]=(bhalf)xc[3];
#pragma unroll
    for (int nt = 0; nt < 12; ++nt) {
      bhalf8 bfrag = *(const bhalf8*)(wrow + (size_t)nt*16*DIN + kk*32);
      acc[nt] = __builtin_amdgcn_mfma_f32_16x16x32_bf16(a, bfrag, acc[nt], 0, 0, 0);
    }
  }

#pragma unroll
  for (int nt = 0; nt < 8; ++nt) {
    bhalf* dst = (nt < 4) ? qb : kb;
    int col = (nt & 3)*16 + r16;
#pragma unroll
    for (int rr = 0; rr < 4; ++rr) {
      int tok = tokbase + g*4 + rr;
      dst[(size_t)tok*DOUT + col] = (bhalf)acc[nt][rr];
    }
  }
#pragma unroll
  for (int nt = 8; nt < 12; ++nt) {
#pragma unroll
    for (int rr = 0; rr < 4; ++rr) {
      vlds[wv][(nt-8)*16 + r16][g*4 + rr] = (bhalf)acc[nt][rr];
    }
  }
  __syncthreads();
  {
    int f      = threadIdx.x & 63;
    int tb     = blockIdx.x*64 + wv*16;
    int b      = (blockIdx.x*64) >> 11;
    int tokloc = tb & 2047;
    bhalf8 v0 = *(const bhalf8*)&vlds[wv][f][0];
    bhalf8 v1 = *(const bhalf8*)&vlds[wv][f][8];
    bhalf* dst = vtb + (size_t)b*(DOUT*SEQ) + (size_t)f*SEQ + tokloc;
    *(bhalf8*)dst       = v0;
    *(bhalf8*)(dst + 8) = v1;
  }
}

// ---------------------------------------------------------------------------
// Flash attention, fully-swapped 32x32 layout. Block = 32 q-rows, 4 waves,
// wave wv covers kv [wv*512, wv*512+512). lane&31 = q throughout:
//   S^T = mfma(K,Q): C[kv=crow(r,hi)][q=lane&31]
//   O^T = mfma(V^T,P): C[d=crow(r,hi)+32dt][q=lane&31]
// crow(r,hi) = (r&3)+8*(r>>2)+4*hi. Rescale alpha is lane-uniform (no shfl).
__device__ inline unsigned pack2(float lo, float hi_) {
  unsigned short a = __builtin_bit_cast(unsigned short, (bhalf)lo);
  unsigned short b = __builtin_bit_cast(unsigned short, (bhalf)hi_);
  return ((unsigned)b << 16) | a;
}
__device__ inline bhalf8 mk8(unsigned a, unsigned b, unsigned c, unsigned d) {
  u32x4 u; u[0]=a; u[1]=b; u[2]=c; u[3]=d;
  return __builtin_bit_cast(bhalf8, u);
}

__global__ __launch_bounds__(256) void attn(const bhalf* __restrict__ qb,
    const bhalf* __restrict__ kb, const bhalf* __restrict__ vtb,
    float* __restrict__ out) {
  __shared__ float po[NSPLIT][64][33];
  __shared__ float pm[NSPLIT][32];
  __shared__ float pl[NSPLIT][32];

  const int lane = threadIdx.x & 63;
  const int wv   = threadIdx.x >> 6;       // kv-split index
  const int l31  = lane & 31;              // q ownership
  const int hi   = lane >> 5;

  // XCD-bijective swizzle: XCD x owns qtiles [x*128, x*128+128) = 2 batches
  const int qtile = (blockIdx.x & 7)*128 + (blockIdx.x >> 3);
  const int qbase = qtile*32;
  const int b     = qbase >> 11;
  const int kv0   = wv * KVPER;

  // Q B-fragments: Q[q=l31][ks*16 + hi*8 + j], ks=0..3
  const bhalf* qp = qb + (size_t)(qbase + l31)*DOUT + hi*8;
  const bhalf8 qf0 = *(const bhalf8*)(qp);
  const bhalf8 qf1 = *(const bhalf8*)(qp + 16);
  const bhalf8 qf2 = *(const bhalf8*)(qp + 32);
  const bhalf8 qf3 = *(const bhalf8*)(qp + 48);

  const bhalf* kp = kb  + ((size_t)b*SEQ + kv0 + l31)*DOUT + hi*8;
  const bhalf* vp = vtb + (size_t)b*DOUT*SEQ + (size_t)l31*SEQ + kv0 + hi*8;

  f32x16 ot0, ot1;
#pragma unroll
  for (int r = 0; r < 16; ++r) { ot0[r] = 0.f; ot1[r] = 0.f; }
  float m = -INFINITY, lsum = 0.f;

  auto loadK = [&](int it, bhalf8& f0, bhalf8& f1, bhalf8& f2, bhalf8& f3) {
    const bhalf* p = kp + (size_t)it*32*DOUT;
    f0 = *(const bhalf8*)(p);
    f1 = *(const bhalf8*)(p + 16);
    f2 = *(const bhalf8*)(p + 32);
    f3 = *(const bhalf8*)(p + 48);
  };
  auto loadV = [&](int it, bhalf8& f0, bhalf8& f1, bhalf8& f2, bhalf8& f3) {
    const bhalf* p = vp + it*32;
    f0 = *(const bhalf8*)(p);             // dt0 sl0
    f1 = *(const bhalf8*)(p + 16);        // dt0 sl1
    f2 = *(const bhalf8*)(p + 32*SEQ);    // dt1 sl0
    f3 = *(const bhalf8*)(p + 32*SEQ + 16);
  };

  auto body = [&](bhalf8 k0, bhalf8 k1, bhalf8 k2, bhalf8 k3,
                  bhalf8 v0, bhalf8 v1, bhalf8 v2, bhalf8 v3) {
    f32x16 s;
#pragma unroll
    for (int r = 0; r < 16; ++r) s[r] = 0.f;
    s = __builtin_amdgcn_mfma_f32_32x32x16_bf16(k0, qf0, s, 0, 0, 0);
    s = __builtin_amdgcn_mfma_f32_32x32x16_bf16(k1, qf1, s, 0, 0, 0);
    s = __builtin_amdgcn_mfma_f32_32x32x16_bf16(k2, qf2, s, 0, 0, 0);
    s = __builtin_amdgcn_mfma_f32_32x32x16_bf16(k3, qf3, s, 0, 0, 0);

    float a0 = fmaxf(fmaxf(s[0], s[1]),  fmaxf(s[2], s[3]));
    float a1 = fmaxf(fmaxf(s[4], s[5]),  fmaxf(s[6], s[7]));
    float a2 = fmaxf(fmaxf(s[8], s[9]),  fmaxf(s[10], s[11]));
    float a3 = fmaxf(fmaxf(s[12], s[13]), fmaxf(s[14], s[15]));
    float bm = fmaxf(fmaxf(a0, a1), fmaxf(a2, a3));
    bm = fmaxf(bm, __shfl_xor(bm, 32));

    if (__any(bm > m)) {
      float mn = fmaxf(m, bm);
      float al = exp2f(m - mn);
      m = mn;
      lsum *= al;
#pragma unroll
      for (int r = 0; r < 16; ++r) { ot0[r] *= al; ot1[r] *= al; }
    }

    f32x16 p;
    float ps = 0.f;
#pragma unroll
    for (int r = 0; r < 16; ++r) { p[r] = exp2f(s[r] - m); ps += p[r]; }
    lsum += ps;

    unsigned w0 = pack2(p[0],  p[1]),  w1 = pack2(p[2],  p[3]);
    unsigned w2 = pack2(p[4],  p[5]),  w3 = pack2(p[6],  p[7]);
    unsigned w4 = pack2(p[8],  p[9]),  w5 = pack2(p[10], p[11]);
    unsigned w6 = pack2(p[12], p[13]), w7 = pack2(p[14], p[15]);
    unsigned x0 = __shfl_xor(w0, 32), x1 = __shfl_xor(w1, 32);
    unsigned x2 = __shfl_xor(w2, 32), x3 = __shfl_xor(w3, 32);
    unsigned x4 = __shfl_xor(w4, 32), x5 = __shfl_xor(w5, 32);
    unsigned x6 = __shfl_xor(w6, 32), x7 = __shfl_xor(w7, 32);
    // P B-frag slot0 (kv 0-15): hi=0 lane holds kv0-7, hi=1 kv8-15
    bhalf8 pf0 = mk8(hi ? x2 : w0, hi ? x3 : w1, hi ? w2 : x0, hi ? w3 : x1);
    bhalf8 pf1 = mk8(hi ? x6 : w4, hi ? x7 : w5, hi ? w6 : x4, hi ? w7 : x5);

    ot0 = __builtin_amdgcn_mfma_f32_32x32x16_bf16(v0, pf0, ot0, 0, 0, 0);
    ot0 = __builtin_amdgcn_mfma_f32_32x32x16_bf16(v1, pf1, ot0, 0, 0, 0);
    ot1 = __builtin_amdgcn_mfma_f32_32x32x16_bf16(v2, pf0, ot1, 0, 0, 0);
    ot1 = __builtin_amdgcn_mfma_f32_32x32x16_bf16(v3, pf1, ot1, 0, 0, 0);
  };

  bhalf8 kA0,kA1,kA2,kA3, vA0,vA1,vA2,vA3;
  bhalf8 kB0,kB1,kB2,kB3, vB0,vB1,vB2,vB3;
  loadK(0, kA0,kA1,kA2,kA3);
  loadV(0, vA0,vA1,vA2,vA3);

  for (int it = 0; it < KVPER/32; it += 2) {
    loadK(it+1, kB0,kB1,kB2,kB3);
    loadV(it+1, vB0,vB1,vB2,vB3);
    body(kA0,kA1,kA2,kA3, vA0,vA1,vA2,vA3);
    if (it + 2 < KVPER/32) {
      loadK(it+2, kA0,kA1,kA2,kA3);
      loadV(it+2, vA0,vA1,vA2,vA3);
    }
    body(kB0,kB1,kB2,kB3, vB0,vB1,vB2,vB3);
  }

  lsum += __shfl_xor(lsum, 32);

  // per-split partials to LDS: po[wv][d][q]
#pragma unroll
  for (int r = 0; r < 16; ++r) {
    int d0 = (r & 3) + 8*(r >> 2) + 4*hi;
    po[wv][d0][l31]      = ot0[r];
    po[wv][32 + d0][l31] = ot1[r];
  }
  if (hi == 0) { pm[wv][l31] = m; pl[wv][l31] = lsum; }
  __syncthreads();

  // combine 4 splits: thread t -> q = t>>3, d in [ (t&7)*8, +8 )
  {
    int q  = threadIdx.x >> 3;
    int dg = (threadIdx.x & 7) * 8;
    float m0 = pm[0][q], m1 = pm[1][q], m2 = pm[2][q], m3 = pm[3][q];
    float M  = fmaxf(fmaxf(m0, m1), fmaxf(m2, m3));
    float w0 = exp2f(m0 - M), w1 = exp2f(m1 - M);
    float w2 = exp2f(m2 - M), w3 = exp2f(m3 - M);
    float L  = pl[0][q]*w0 + pl[1][q]*w1 + pl[2][q]*w2 + pl[3][q]*w3;
    float inv = 1.0f / L;
    float* orow = out + (size_t)(qbase + q)*DOUT + dg;
#pragma unroll
    for (int j = 0; j < 8; ++j) {
      float acc = po[0][dg+j][q]*w0 + po[1][dg+j][q]*w1
                + po[2][dg+j][q]*w2 + po[3][dg+j][q]*w3;
      orow[j] = acc * inv;
    }
  }
}

// ---------------------------------------------------------------------------
extern "C" void kernel_launch(void* const* d_in, const int* in_sizes, int n_in,
                              void* d_out, int out_size, void* d_ws, size_t ws_size,
                              hipStream_t stream) {
  const float* x  = (const float*)d_in[0];
  const float* wk = (const float*)d_in[1];
  float* out = (float*)d_out;

  char* ws = (char*)d_ws;
  bhalf* wt = (bhalf*)(ws);
  bhalf* qq = (bhalf*)(ws + Q_OFF);
  bhalf* kk = (bhalf*)(ws + K_OFF);
  bhalf* vt = (bhalf*)(ws + VT_OFF);

  prep_w  <<<dim3(384),  dim3(256), 0, stream>>>(wk, wt);
  proj_qkv<<<dim3(512),  dim3(256), 0, stream>>>(x, wt, qq, kk, vt);
  attn    <<<dim3(1024), dim3(256), 0, stream>>>(qq, kk, vt, out);
}